// Round 5
// baseline (474.824 us; speedup 1.0000x reference)
//
#include <hip/hip_runtime.h>
#include <hip/hip_bf16.h>

#define DIM 128
#define NN 40000
#define NE 640000

// gfx950 bf16 MFMA fragment types (learn_hip m89/m93/m97):
typedef __attribute__((ext_vector_type(8))) short s16x8;   // 8 bf16 in 4 VGPRs
typedef __attribute__((ext_vector_type(4))) float f32x4;
typedef __attribute__((ext_vector_type(4))) unsigned short u16x4;

__device__ __forceinline__ float bf16_lo(unsigned v) { return __uint_as_float(v << 16); }
__device__ __forceinline__ float bf16_hi(unsigned v) { return __uint_as_float(v & 0xffff0000u); }
__device__ __forceinline__ unsigned short f_to_bf16(float f) {
    unsigned u = __float_as_uint(f);
    u += 0x7fffu + ((u >> 16) & 1u);   // round-to-nearest-even
    return (unsigned short)(u >> 16);
}

// ---------------- diagnostics ----------------
__global__ void fill_const_f32(float* __restrict__ out, int n, float v) {
    int i = blockIdx.x * blockDim.x + threadIdx.x;
    if (i < n) out[i] = v;
}

__global__ void zero_ints(int* __restrict__ p, int n) {
    int i = blockIdx.x * blockDim.x + threadIdx.x;
    if (i < n) p[i] = 0;
}

// ---------------- fp32 -> bf16 conversion (4 elems/thread) ----------------
__global__ void cvt_f32_bf16(const float* __restrict__ src,
                             unsigned short* __restrict__ dst, int n4) {
    int i = blockIdx.x * blockDim.x + threadIdx.x;
    if (i >= n4) return;
    f32x4 v = *(const f32x4*)(src + 4 * (size_t)i);
    u16x4 o;
    o.x = f_to_bf16(v.x); o.y = f_to_bf16(v.y);
    o.z = f_to_bf16(v.z); o.w = f_to_bf16(v.w);
    *(u16x4*)(dst + 4 * (size_t)i) = o;
}

// ---------------- edge_index dtype detection ----------------
// int64 passthrough: odd 32-bit words (high halves of elems 0..63, values <
// 40000) are ALL zero. int32: those words are random src ids — never all 0.
__global__ void detect_fmt(const int* __restrict__ ei, int* __restrict__ flag) {
    if (threadIdx.x == 0 && blockIdx.x == 0) {
        int nz = 0;
        for (int i = 0; i < 64; ++i) nz |= ei[2 * i + 1];
        *flag = (nz == 0) ? 1 : 0;
    }
}

// ---------------- CSR build ----------------

__global__ void count_deg(const int* __restrict__ ei, const int* __restrict__ fmt,
                          int* __restrict__ deg) {
    int e = blockIdx.x * blockDim.x + threadIdx.x;
    if (e >= NE) return;
    int dst = (*fmt) ? ei[2 * (NE + e)] : ei[NE + e];
    if ((unsigned)dst < (unsigned)NN) atomicAdd(&deg[dst], 1);
}

__global__ void scan_deg(const int* __restrict__ deg, int* __restrict__ row_ptr,
                         int* __restrict__ cursor) {
    __shared__ int partial[1024];
    int tid = threadIdx.x;
    const int CH = (NN + 1023) >> 10;   // 40
    int base = tid * CH;
    int sum = 0;
    for (int i = 0; i < CH; ++i) {
        int idx = base + i;
        if (idx < NN) sum += deg[idx];
    }
    partial[tid] = sum;
    __syncthreads();
    for (int off = 1; off < 1024; off <<= 1) {
        int v = 0;
        if (tid >= off) v = partial[tid - off];
        __syncthreads();
        if (tid >= off) partial[tid] += v;
        __syncthreads();
    }
    int run = partial[tid] - sum;   // exclusive prefix
    for (int i = 0; i < CH; ++i) {
        int idx = base + i;
        if (idx < NN) {
            row_ptr[idx] = run;
            cursor[idx] = run;
            run += deg[idx];
        }
    }
    if (tid == 1023) row_ptr[NN] = partial[1023];
}

__global__ void fill_csr(const int* __restrict__ ei, const int* __restrict__ fmt,
                         int* __restrict__ cursor, int* __restrict__ sorted_src) {
    int e = blockIdx.x * blockDim.x + threadIdx.x;
    if (e >= NE) return;
    int src, dst;
    if (*fmt) { src = ei[2 * e]; dst = ei[2 * (NE + e)]; }
    else      { src = ei[e];     dst = ei[NE + e]; }
    if ((unsigned)dst >= (unsigned)NN) return;
    int pos = atomicAdd(&cursor[dst], 1);
    if ((unsigned)pos < (unsigned)NE) sorted_src[pos] = src;
}

// ---------------- mean aggregation: one wave per destination node ----------------
// in/out are bf16 [N,128]; accumulate fp32.

__global__ void aggregate(const unsigned short* __restrict__ xin,
                          const int* __restrict__ row_ptr,
                          const int* __restrict__ sorted_src,
                          unsigned short* __restrict__ mean_out) {
    int lane = threadIdx.x & 63;
    int wv = threadIdx.x >> 6;
    int n = blockIdx.x * 4 + wv;
    if (n >= NN) return;
    int start = row_ptr[n], end = row_ptr[n + 1];
    if (start < 0) start = 0;
    if (end > NE) end = NE;
    float a0 = 0.f, a1 = 0.f;
    int off = lane * 2;
    for (int i = start; i < end; ++i) {
        int s = sorted_src[i];
        if ((unsigned)s >= (unsigned)NN) continue;
        unsigned v = *(const unsigned*)(xin + (size_t)s * DIM + off);
        a0 += bf16_lo(v);
        a1 += bf16_hi(v);
    }
    int d = end - start;
    float inv = 1.f / (float)(d > 1 ? d : 1);
    a0 *= inv; a1 *= inv;
    unsigned out = (unsigned)f_to_bf16(a0) | ((unsigned)f_to_bf16(a1) << 16);
    *(unsigned*)(mean_out + (size_t)n * DIM + off) = out;
}

// ---------------- fused SAGE linear: relu(mean@Wl^T + b + h@Wr^T) ----------------
// mfma_f32_16x16x32_bf16 layouts (m89/m120-verified):
//   A: A[m=lane&15][k=quad*8+j]; B: B[k=quad*8+j][n=lane&15] (=W[col][k..k+7]);
//   C/D: col=lane&15, row=quad*4+reg.
// WRITE_F32: epilogue writes fp32 (final output) vs bf16 (h1 intermediate).

template <bool WRITE_F32>
__global__ __launch_bounds__(256) void sage_gemm(
    const unsigned short* __restrict__ mean,   // [N,128] bf16
    const unsigned short* __restrict__ hself,  // [N,128] bf16
    const unsigned short* __restrict__ Wl,     // [128,128] bf16, row-major [out,in]
    const unsigned short* __restrict__ Wr,
    const float* __restrict__ bias,            // [128] fp32
    void* __restrict__ outv) {
    int lane = threadIdx.x & 63;
    int wv = threadIdx.x >> 6;
    int quad = lane >> 4;
    int lid = lane & 15;
    int row0 = blockIdx.x * 16;
    int col0 = blockIdx.y * 64 + wv * 16;
    int arow = row0 + lid;
    int bcol = col0 + lid;

    f32x4 acc = {0.f, 0.f, 0.f, 0.f};

    const unsigned short* aptr = mean + (size_t)arow * DIM + quad * 8;
    const unsigned short* bptr = Wl + (size_t)bcol * DIM + quad * 8;
#pragma unroll
    for (int kb = 0; kb < 4; ++kb) {
        s16x8 a = *(const s16x8*)(aptr + kb * 32);
        s16x8 b = *(const s16x8*)(bptr + kb * 32);
        acc = __builtin_amdgcn_mfma_f32_16x16x32_bf16(a, b, acc, 0, 0, 0);
    }
    aptr = hself + (size_t)arow * DIM + quad * 8;
    bptr = Wr + (size_t)bcol * DIM + quad * 8;
#pragma unroll
    for (int kb = 0; kb < 4; ++kb) {
        s16x8 a = *(const s16x8*)(aptr + kb * 32);
        s16x8 b = *(const s16x8*)(bptr + kb * 32);
        acc = __builtin_amdgcn_mfma_f32_16x16x32_bf16(a, b, acc, 0, 0, 0);
    }

    float bv = bias[bcol];
#pragma unroll
    for (int r = 0; r < 4; ++r) {
        int orow = row0 + quad * 4 + r;
        float v = acc[r] + bv;
        if (v != v) v = 137.0f;            // NaN sentinel (diagnostic)
        else v = v > 0.f ? v : 0.f;        // relu
        if (WRITE_F32)
            ((float*)outv)[(size_t)orow * DIM + bcol] = v;
        else
            ((unsigned short*)outv)[(size_t)orow * DIM + bcol] = f_to_bf16(v);
    }
}

// ---------------- launch ----------------

extern "C" void kernel_launch(void* const* d_in, const int* in_sizes, int n_in,
                              void* d_out, int out_size, void* d_ws, size_t ws_size,
                              hipStream_t stream) {
    const float* x   = (const float*)d_in[0];
    const int*   ei  = (const int*)d_in[1];
    const float* W1l = (const float*)d_in[2];
    const float* b1l = (const float*)d_in[3];
    const float* W1r = (const float*)d_in[4];
    const float* W2l = (const float*)d_in[5];
    const float* b2l = (const float*)d_in[6];
    const float* W2r = (const float*)d_in[7];
    float* out = (float*)d_out;

    const int OUT_ELEMS = NN * DIM;        // 5,120,000

    // canary: 1.0 everywhere — if later kernels never run, absmax ~= 3.28.
    fill_const_f32<<<(OUT_ELEMS + 255) / 256, 256, 0, stream>>>(out, OUT_ELEMS, 1.0f);

    // workspace layout (256B-aligned)
    const size_t OFF_DEG  = 0;             // N ints
    const size_t OFF_ROW  = 163840;        // N+1 ints
    const size_t OFF_CUR  = 327680;        // N ints
    const size_t OFF_FMT  = 491264;        // 1 int
    const size_t OFF_SRT  = 491520;        // E ints
    const size_t OFF_WB   = 3051520;       // 4 * 128*128 bf16 = 131,072 B
    const size_t OFF_XB   = 3182592;       // N*128 bf16
    const size_t OFF_MEAN = 13422592;      // N*128 bf16
    const size_t OFF_H1   = 23662592;      // N*128 bf16
    const size_t NEEDED   = 33902592;

    if (ws_size < NEEDED) {
        // sentinel 50.0: absmax ~= 50 => workspace too small
        fill_const_f32<<<(OUT_ELEMS + 255) / 256, 256, 0, stream>>>(out, OUT_ELEMS, 50.0f);
        return;
    }

    char* ws = (char*)d_ws;
    int* deg     = (int*)(ws + OFF_DEG);
    int* row_ptr = (int*)(ws + OFF_ROW);
    int* cursor  = (int*)(ws + OFF_CUR);
    int* fmtflag = (int*)(ws + OFF_FMT);
    int* sorted  = (int*)(ws + OFF_SRT);
    unsigned short* Wb    = (unsigned short*)(ws + OFF_WB);
    unsigned short* W1lb  = Wb;
    unsigned short* W1rb  = Wb + 16384;
    unsigned short* W2lb  = Wb + 32768;
    unsigned short* W2rb  = Wb + 49152;
    unsigned short* xb    = (unsigned short*)(ws + OFF_XB);
    unsigned short* meanb = (unsigned short*)(ws + OFF_MEAN);
    unsigned short* h1b   = (unsigned short*)(ws + OFF_H1);

    // conversions fp32 -> bf16
    cvt_f32_bf16<<<(OUT_ELEMS / 4 + 255) / 256, 256, 0, stream>>>(x, xb, OUT_ELEMS / 4);
    cvt_f32_bf16<<<16, 256, 0, stream>>>(W1l, W1lb, 4096);
    cvt_f32_bf16<<<16, 256, 0, stream>>>(W1r, W1rb, 4096);
    cvt_f32_bf16<<<16, 256, 0, stream>>>(W2l, W2lb, 4096);
    cvt_f32_bf16<<<16, 256, 0, stream>>>(W2r, W2rb, 4096);

    // CSR build
    zero_ints<<<(NN + 255) / 256, 256, 0, stream>>>(deg, NN);
    detect_fmt<<<1, 64, 0, stream>>>(ei, fmtflag);
    count_deg<<<(NE + 255) / 256, 256, 0, stream>>>(ei, fmtflag, deg);
    scan_deg<<<1, 1024, 0, stream>>>(deg, row_ptr, cursor);
    fill_csr<<<(NE + 255) / 256, 256, 0, stream>>>(ei, fmtflag, cursor, sorted);

    // layer 1: h1 = relu(mean(x)@W1l^T + b1l + x@W1r^T)   (bf16 out)
    aggregate<<<(NN + 3) / 4, 256, 0, stream>>>(xb, row_ptr, sorted, meanb);
    sage_gemm<false><<<dim3(NN / 16, 2), 256, 0, stream>>>(meanb, xb, W1lb, W1rb, b1l, h1b);

    // layer 2: out = relu(mean(h1)@W2l^T + b2l + h1@W2r^T)   (fp32 out)
    aggregate<<<(NN + 3) / 4, 256, 0, stream>>>(h1b, row_ptr, sorted, meanb);
    sage_gemm<true><<<dim3(NN / 16, 2), 256, 0, stream>>>(meanb, h1b, W2lb, W2rb, b2l, out);
}

// Round 6
// 294.225 us; speedup vs baseline: 1.6138x; 1.6138x over previous
//
#include <hip/hip_runtime.h>
#include <hip/hip_bf16.h>

#define DIM 128
#define NN 40000
#define NE 640000
#define NBLK ((NN + 255) / 256)   // 157

// gfx950 bf16 MFMA fragment types (learn_hip m89/m93/m97):
typedef __attribute__((ext_vector_type(8))) short s16x8;   // 8 bf16 in 4 VGPRs
typedef __attribute__((ext_vector_type(4))) float f32x4;
typedef __attribute__((ext_vector_type(4))) unsigned short u16x4;
typedef __attribute__((ext_vector_type(4))) unsigned int u32x4;

__device__ __forceinline__ float bf16_lo(unsigned v) { return __uint_as_float(v << 16); }
__device__ __forceinline__ float bf16_hi(unsigned v) { return __uint_as_float(v & 0xffff0000u); }
__device__ __forceinline__ unsigned short f_to_bf16(float f) {
    unsigned u = __float_as_uint(f);
    u += 0x7fffu + ((u >> 16) & 1u);   // round-to-nearest-even
    return (unsigned short)(u >> 16);
}

__global__ void fill_const_f32(float* __restrict__ out, int n, float v) {
    int i = blockIdx.x * blockDim.x + threadIdx.x;
    if (i < n) out[i] = v;
}

__global__ void zero_ints(int* __restrict__ p, int n) {
    int i = blockIdx.x * blockDim.x + threadIdx.x;
    if (i < n) p[i] = 0;
}

// ---------------- fp32 -> bf16 conversions ----------------
__global__ void cvt_f32_bf16(const float* __restrict__ src,
                             unsigned short* __restrict__ dst, int n4) {
    int i = blockIdx.x * blockDim.x + threadIdx.x;
    if (i >= n4) return;
    f32x4 v = *(const f32x4*)(src + 4 * (size_t)i);
    u16x4 o;
    o.x = f_to_bf16(v.x); o.y = f_to_bf16(v.y);
    o.z = f_to_bf16(v.z); o.w = f_to_bf16(v.w);
    *(u16x4*)(dst + 4 * (size_t)i) = o;
}

// all 4 weight matrices in one launch: grid (16, 4), block 256
__global__ void cvt_weights(const float* __restrict__ w0, const float* __restrict__ w1,
                            const float* __restrict__ w2, const float* __restrict__ w3,
                            unsigned short* __restrict__ dst) {
    int m = blockIdx.y;
    const float* src = (m == 0) ? w0 : (m == 1) ? w1 : (m == 2) ? w2 : w3;
    int i = blockIdx.x * blockDim.x + threadIdx.x;   // 0..4095, 4 elems each
    f32x4 v = *(const f32x4*)(src + 4 * (size_t)i);
    u16x4 o;
    o.x = f_to_bf16(v.x); o.y = f_to_bf16(v.y);
    o.z = f_to_bf16(v.z); o.w = f_to_bf16(v.w);
    *(u16x4*)(dst + (size_t)m * 16384 + 4 * (size_t)i) = o;
}

// ---------------- edge_index dtype detection ----------------
__global__ void detect_fmt(const int* __restrict__ ei, int* __restrict__ flag) {
    if (threadIdx.x == 0 && blockIdx.x == 0) {
        int nz = 0;
        for (int i = 0; i < 64; ++i) nz |= ei[2 * i + 1];
        *flag = (nz == 0) ? 1 : 0;   // 1 = int64 passthrough
    }
}

// ---------------- CSR build ----------------

__global__ void count_deg(const int* __restrict__ ei, const int* __restrict__ fmt,
                          int* __restrict__ deg) {
    int e = blockIdx.x * blockDim.x + threadIdx.x;
    if (e >= NE) return;
    int dst = (*fmt) ? ei[2 * (NE + e)] : ei[NE + e];
    if ((unsigned)dst < (unsigned)NN) atomicAdd(&deg[dst], 1);
}

// hierarchical exclusive scan: block_sums -> scan_bsums -> scan_block
__global__ void block_sums(const int* __restrict__ deg, int* __restrict__ bsum) {
    __shared__ int sh[256];
    int i = blockIdx.x * 256 + threadIdx.x;
    sh[threadIdx.x] = (i < NN) ? deg[i] : 0;
    __syncthreads();
    for (int off = 128; off > 0; off >>= 1) {
        if (threadIdx.x < off) sh[threadIdx.x] += sh[threadIdx.x + off];
        __syncthreads();
    }
    if (threadIdx.x == 0) bsum[blockIdx.x] = sh[0];
}

__global__ void scan_bsums(int* __restrict__ bsum, int nb) {
    __shared__ int sh[256];
    int t = threadIdx.x;
    int v = (t < nb) ? bsum[t] : 0;
    sh[t] = v;
    __syncthreads();
    for (int off = 1; off < 256; off <<= 1) {
        int u = (t >= off) ? sh[t - off] : 0;
        __syncthreads();
        sh[t] += u;
        __syncthreads();
    }
    if (t < nb) bsum[t] = sh[t] - v;   // exclusive
}

__global__ void scan_block(const int* __restrict__ deg, const int* __restrict__ bsum,
                           int* __restrict__ row_ptr, int* __restrict__ cursor) {
    __shared__ int sh[256];
    int t = threadIdx.x;
    int i = blockIdx.x * 256 + t;
    int v = (i < NN) ? deg[i] : 0;
    sh[t] = v;
    __syncthreads();
    for (int off = 1; off < 256; off <<= 1) {
        int u = (t >= off) ? sh[t - off] : 0;
        __syncthreads();
        sh[t] += u;
        __syncthreads();
    }
    int excl = sh[t] - v + bsum[blockIdx.x];
    if (i < NN) { row_ptr[i] = excl; cursor[i] = excl; }
    if (i == NN - 1) row_ptr[NN] = excl + v;
}

__global__ void fill_csr(const int* __restrict__ ei, const int* __restrict__ fmt,
                         int* __restrict__ cursor, int* __restrict__ sorted_src) {
    int e = blockIdx.x * blockDim.x + threadIdx.x;
    if (e >= NE) return;
    int src, dst;
    if (*fmt) { src = ei[2 * e]; dst = ei[2 * (NE + e)]; }
    else      { src = ei[e];     dst = ei[NE + e]; }
    if ((unsigned)dst >= (unsigned)NN) return;
    int pos = atomicAdd(&cursor[dst], 1);
    if ((unsigned)pos < (unsigned)NE) sorted_src[pos] = src;
}

// ---------------- mean aggregation ----------------
// One wave per dst node. 16 lanes x 16 B cover one 256 B row; 4 edges in
// flight per iteration (grp = lane>>4). fp32 partials, shfl_xor combine.

__global__ void aggregate(const unsigned short* __restrict__ xin,
                          const int* __restrict__ row_ptr,
                          const int* __restrict__ sorted_src,
                          unsigned short* __restrict__ mean_out) {
    int lane = threadIdx.x & 63;
    int wv = threadIdx.x >> 6;
    int n = blockIdx.x * 4 + wv;
    if (n >= NN) return;
    int start = row_ptr[n], end = row_ptr[n + 1];
    if (start < 0) start = 0;
    if (end > NE) end = NE;
    int grp = lane >> 4;    // 0..3: edge slot
    int lid = lane & 15;    // 16 lanes per row, 8 bf16 (16 B) each
    float acc[8] = {0.f, 0.f, 0.f, 0.f, 0.f, 0.f, 0.f, 0.f};
    for (int i = start + grp; i < end; i += 4) {
        int s = sorted_src[i];
        if ((unsigned)s >= (unsigned)NN) continue;
        u32x4 v = *(const u32x4*)(xin + (size_t)s * DIM + lid * 8);
        acc[0] += bf16_lo(v.x); acc[1] += bf16_hi(v.x);
        acc[2] += bf16_lo(v.y); acc[3] += bf16_hi(v.y);
        acc[4] += bf16_lo(v.z); acc[5] += bf16_hi(v.z);
        acc[6] += bf16_lo(v.w); acc[7] += bf16_hi(v.w);
    }
#pragma unroll
    for (int k = 0; k < 8; ++k) {
        acc[k] += __shfl_xor(acc[k], 16, 64);
        acc[k] += __shfl_xor(acc[k], 32, 64);
    }
    if (grp == 0) {
        int d = end - start;
        float inv = 1.f / (float)(d > 1 ? d : 1);
        u32x4 o;
        o.x = (unsigned)f_to_bf16(acc[0] * inv) | ((unsigned)f_to_bf16(acc[1] * inv) << 16);
        o.y = (unsigned)f_to_bf16(acc[2] * inv) | ((unsigned)f_to_bf16(acc[3] * inv) << 16);
        o.z = (unsigned)f_to_bf16(acc[4] * inv) | ((unsigned)f_to_bf16(acc[5] * inv) << 16);
        o.w = (unsigned)f_to_bf16(acc[6] * inv) | ((unsigned)f_to_bf16(acc[7] * inv) << 16);
        *(u32x4*)(mean_out + (size_t)n * DIM + lid * 8) = o;
    }
}

// ---------------- fused SAGE linear: relu(mean@Wl^T + b + h@Wr^T) ----------------
// mfma_f32_16x16x32_bf16 layouts (m89/m120-verified):
//   A: A[m=lane&15][k=quad*8+j]; B: B[k=quad*8+j][n=lane&15] = W[col][k..k+7];
//   C/D: col=lane&15, row=quad*4+reg.

template <bool WRITE_F32>
__global__ __launch_bounds__(256) void sage_gemm(
    const unsigned short* __restrict__ mean,   // [N,128] bf16
    const unsigned short* __restrict__ hself,  // [N,128] bf16
    const unsigned short* __restrict__ Wl,     // [128,128] bf16
    const unsigned short* __restrict__ Wr,
    const float* __restrict__ bias,            // [128] fp32
    void* __restrict__ outv) {
    int lane = threadIdx.x & 63;
    int wv = threadIdx.x >> 6;
    int quad = lane >> 4;
    int lid = lane & 15;
    int row0 = blockIdx.x * 16;
    int col0 = blockIdx.y * 64 + wv * 16;
    int arow = row0 + lid;
    int bcol = col0 + lid;

    f32x4 acc = {0.f, 0.f, 0.f, 0.f};

    const unsigned short* aptr = mean + (size_t)arow * DIM + quad * 8;
    const unsigned short* bptr = Wl + (size_t)bcol * DIM + quad * 8;
#pragma unroll
    for (int kb = 0; kb < 4; ++kb) {
        s16x8 a = *(const s16x8*)(aptr + kb * 32);
        s16x8 b = *(const s16x8*)(bptr + kb * 32);
        acc = __builtin_amdgcn_mfma_f32_16x16x32_bf16(a, b, acc, 0, 0, 0);
    }
    aptr = hself + (size_t)arow * DIM + quad * 8;
    bptr = Wr + (size_t)bcol * DIM + quad * 8;
#pragma unroll
    for (int kb = 0; kb < 4; ++kb) {
        s16x8 a = *(const s16x8*)(aptr + kb * 32);
        s16x8 b = *(const s16x8*)(bptr + kb * 32);
        acc = __builtin_amdgcn_mfma_f32_16x16x32_bf16(a, b, acc, 0, 0, 0);
    }

    float bv = bias[bcol];
#pragma unroll
    for (int r = 0; r < 4; ++r) {
        int orow = row0 + quad * 4 + r;
        float v = fmaxf(acc[r] + bv, 0.f);   // relu (NaN -> 0)
        if (WRITE_F32)
            ((float*)outv)[(size_t)orow * DIM + bcol] = v;
        else
            ((unsigned short*)outv)[(size_t)orow * DIM + bcol] = f_to_bf16(v);
    }
}

// ---------------- launch ----------------

extern "C" void kernel_launch(void* const* d_in, const int* in_sizes, int n_in,
                              void* d_out, int out_size, void* d_ws, size_t ws_size,
                              hipStream_t stream) {
    const float* x   = (const float*)d_in[0];
    const int*   ei  = (const int*)d_in[1];
    const float* W1l = (const float*)d_in[2];
    const float* b1l = (const float*)d_in[3];
    const float* W1r = (const float*)d_in[4];
    const float* b2l = (const float*)d_in[6];
    const float* W2l = (const float*)d_in[5];
    const float* W2r = (const float*)d_in[7];
    float* out = (float*)d_out;

    const int OUT_ELEMS = NN * DIM;        // 5,120,000

    // workspace layout (256B-aligned; bsum tucked into row_ptr region slack)
    const size_t OFF_DEG  = 0;             // N ints
    const size_t OFF_ROW  = 163840;        // N+1 ints (160,004 B of 163,840)
    const size_t OFF_BSUM = 324608;        // NBLK ints (fits in ROW slack)
    const size_t OFF_CUR  = 327680;        // N ints
    const size_t OFF_FMT  = 491264;        // 1 int
    const size_t OFF_SRT  = 491520;        // E ints
    const size_t OFF_WB   = 3051520;       // 4 * 16384 bf16
    const size_t OFF_XB   = 3182592;       // N*128 bf16
    const size_t OFF_MEAN = 13422592;      // N*128 bf16
    const size_t OFF_H1   = 23662592;      // N*128 bf16
    const size_t NEEDED   = 33902592;

    if (ws_size < NEEDED) {
        fill_const_f32<<<(OUT_ELEMS + 255) / 256, 256, 0, stream>>>(out, OUT_ELEMS, 50.0f);
        return;
    }

    char* ws = (char*)d_ws;
    int* deg     = (int*)(ws + OFF_DEG);
    int* row_ptr = (int*)(ws + OFF_ROW);
    int* bsum    = (int*)(ws + OFF_BSUM);
    int* cursor  = (int*)(ws + OFF_CUR);
    int* fmtflag = (int*)(ws + OFF_FMT);
    int* sorted  = (int*)(ws + OFF_SRT);
    unsigned short* Wb    = (unsigned short*)(ws + OFF_WB);
    unsigned short* xb    = (unsigned short*)(ws + OFF_XB);
    unsigned short* meanb = (unsigned short*)(ws + OFF_MEAN);
    unsigned short* h1b   = (unsigned short*)(ws + OFF_H1);

    // conversions fp32 -> bf16
    cvt_f32_bf16<<<(OUT_ELEMS / 4 + 255) / 256, 256, 0, stream>>>(x, xb, OUT_ELEMS / 4);
    cvt_weights<<<dim3(16, 4), 256, 0, stream>>>(W1l, W1r, W2l, W2r, Wb);
    unsigned short* W1lb = Wb;
    unsigned short* W1rb = Wb + 16384;
    unsigned short* W2lb = Wb + 32768;
    unsigned short* W2rb = Wb + 49152;

    // CSR build
    zero_ints<<<NBLK, 256, 0, stream>>>(deg, NN);
    detect_fmt<<<1, 64, 0, stream>>>(ei, fmtflag);
    count_deg<<<(NE + 255) / 256, 256, 0, stream>>>(ei, fmtflag, deg);
    block_sums<<<NBLK, 256, 0, stream>>>(deg, bsum);
    scan_bsums<<<1, 256, 0, stream>>>(bsum, NBLK);
    scan_block<<<NBLK, 256, 0, stream>>>(deg, bsum, row_ptr, cursor);
    fill_csr<<<(NE + 255) / 256, 256, 0, stream>>>(ei, fmtflag, cursor, sorted);

    // layer 1: h1 = relu(mean(x)@W1l^T + b1l + x@W1r^T)   (bf16 out)
    aggregate<<<(NN + 3) / 4, 256, 0, stream>>>(xb, row_ptr, sorted, meanb);
    sage_gemm<false><<<dim3(NN / 16, 2), 256, 0, stream>>>(meanb, xb, W1lb, W1rb, b1l, h1b);

    // layer 2: out = relu(mean(h1)@W2l^T + b2l + h1@W2r^T)   (fp32 out)
    aggregate<<<(NN + 3) / 4, 256, 0, stream>>>(h1b, row_ptr, sorted, meanb);
    sage_gemm<true><<<dim3(NN / 16, 2), 256, 0, stream>>>(meanb, h1b, W2lb, W2rb, b2l, out);
}

// Round 7
// 252.972 us; speedup vs baseline: 1.8770x; 1.1631x over previous
//
#include <hip/hip_runtime.h>
#include <hip/hip_bf16.h>

#define DIM 128
#define NN 40000
#define NE 640000
#define NBLK ((NN + 255) / 256)   // 157

// gfx950 bf16 MFMA fragment types (learn_hip m89/m93/m97):
typedef __attribute__((ext_vector_type(8))) short s16x8;   // 8 bf16 in 4 VGPRs
typedef __attribute__((ext_vector_type(4))) float f32x4;
typedef __attribute__((ext_vector_type(4))) unsigned short u16x4;
typedef __attribute__((ext_vector_type(4))) unsigned int u32x4;

__device__ __forceinline__ float bf16_lo(unsigned v) { return __uint_as_float(v << 16); }
__device__ __forceinline__ float bf16_hi(unsigned v) { return __uint_as_float(v & 0xffff0000u); }
__device__ __forceinline__ unsigned short f_to_bf16(float f) {
    unsigned u = __float_as_uint(f);
    u += 0x7fffu + ((u >> 16) & 1u);   // round-to-nearest-even
    return (unsigned short)(u >> 16);
}

__global__ void fill_const_f32(float* __restrict__ out, int n, float v) {
    int i = blockIdx.x * blockDim.x + threadIdx.x;
    if (i < n) out[i] = v;
}

__global__ void zero_ints(int* __restrict__ p, int n) {
    int i = blockIdx.x * blockDim.x + threadIdx.x;
    if (i < n) p[i] = 0;
}

// ---------------- fp32 -> bf16 conversions ----------------
__global__ void cvt_f32_bf16(const float* __restrict__ src,
                             unsigned short* __restrict__ dst, int n4) {
    int i = blockIdx.x * blockDim.x + threadIdx.x;
    if (i >= n4) return;
    f32x4 v = *(const f32x4*)(src + 4 * (size_t)i);
    u16x4 o;
    o.x = f_to_bf16(v.x); o.y = f_to_bf16(v.y);
    o.z = f_to_bf16(v.z); o.w = f_to_bf16(v.w);
    *(u16x4*)(dst + 4 * (size_t)i) = o;
}

// all 4 weight matrices in one launch: grid (16, 4), block 256
__global__ void cvt_weights(const float* __restrict__ w0, const float* __restrict__ w1,
                            const float* __restrict__ w2, const float* __restrict__ w3,
                            unsigned short* __restrict__ dst) {
    int m = blockIdx.y;
    const float* src = (m == 0) ? w0 : (m == 1) ? w1 : (m == 2) ? w2 : w3;
    int i = blockIdx.x * blockDim.x + threadIdx.x;
    f32x4 v = *(const f32x4*)(src + 4 * (size_t)i);
    u16x4 o;
    o.x = f_to_bf16(v.x); o.y = f_to_bf16(v.y);
    o.z = f_to_bf16(v.z); o.w = f_to_bf16(v.w);
    *(u16x4*)(dst + (size_t)m * 16384 + 4 * (size_t)i) = o;
}

// ---------------- edge_index dtype detection (64-lane parallel) ----------------
__global__ void detect_fmt(const int* __restrict__ ei, int* __restrict__ flag) {
    int lane = threadIdx.x;
    int w = ei[2 * lane + 1];
    unsigned long long m = __ballot(w == 0);
    if (lane == 0) *flag = (m == ~0ull) ? 1 : 0;   // 1 = int64 passthrough
}

// ---------------- CSR build ----------------

__global__ void count_deg(const int* __restrict__ ei, const int* __restrict__ fmt,
                          int* __restrict__ deg) {
    int e = blockIdx.x * blockDim.x + threadIdx.x;
    if (e >= NE) return;
    int dst = (*fmt) ? ((const int2*)ei)[NE + e].x : ei[NE + e];
    if ((unsigned)dst < (unsigned)NN) atomicAdd(&deg[dst], 1);
}

// hierarchical exclusive scan: block_sums -> scan_bsums -> scan_block
__global__ void block_sums(const int* __restrict__ deg, int* __restrict__ bsum) {
    __shared__ int sh[256];
    int i = blockIdx.x * 256 + threadIdx.x;
    sh[threadIdx.x] = (i < NN) ? deg[i] : 0;
    __syncthreads();
    for (int off = 128; off > 0; off >>= 1) {
        if (threadIdx.x < off) sh[threadIdx.x] += sh[threadIdx.x + off];
        __syncthreads();
    }
    if (threadIdx.x == 0) bsum[blockIdx.x] = sh[0];
}

__global__ void scan_bsums(int* __restrict__ bsum, int nb) {
    __shared__ int sh[256];
    int t = threadIdx.x;
    int v = (t < nb) ? bsum[t] : 0;
    sh[t] = v;
    __syncthreads();
    for (int off = 1; off < 256; off <<= 1) {
        int u = (t >= off) ? sh[t - off] : 0;
        __syncthreads();
        sh[t] += u;
        __syncthreads();
    }
    if (t < nb) bsum[t] = sh[t] - v;   // exclusive
}

__global__ void scan_block(const int* __restrict__ deg, const int* __restrict__ bsum,
                           int* __restrict__ row_ptr, int* __restrict__ cursor) {
    __shared__ int sh[256];
    int t = threadIdx.x;
    int i = blockIdx.x * 256 + t;
    int v = (i < NN) ? deg[i] : 0;
    sh[t] = v;
    __syncthreads();
    for (int off = 1; off < 256; off <<= 1) {
        int u = (t >= off) ? sh[t - off] : 0;
        __syncthreads();
        sh[t] += u;
        __syncthreads();
    }
    int excl = sh[t] - v + bsum[blockIdx.x];
    if (i < NN) { row_ptr[i] = excl; cursor[i] = excl; }
    if (i == NN - 1) row_ptr[NN] = excl + v;
}

__global__ void fill_csr(const int* __restrict__ ei, const int* __restrict__ fmt,
                         int* __restrict__ cursor, int* __restrict__ sorted_src) {
    int e = blockIdx.x * blockDim.x + threadIdx.x;
    if (e >= NE) return;
    int src, dst;
    if (*fmt) {
        src = ((const int2*)ei)[e].x;
        dst = ((const int2*)ei)[NE + e].x;
    } else {
        src = ei[e];
        dst = ei[NE + e];
    }
    if ((unsigned)dst >= (unsigned)NN) return;
    int pos = atomicAdd(&cursor[dst], 1);
    if ((unsigned)pos < (unsigned)NE) sorted_src[pos] = src;
}

// ---------------- mean aggregation ----------------
// One wave per dst node; 16 lanes x 16 B per row, 4 edge slots (grp), edge
// loop unrolled x2 -> 2 independent 16 B gathers in flight per lane.

__global__ void aggregate(const unsigned short* __restrict__ xin,
                          const int* __restrict__ row_ptr,
                          const int* __restrict__ sorted_src,
                          unsigned short* __restrict__ mean_out) {
    int lane = threadIdx.x & 63;
    int wv = threadIdx.x >> 6;
    int n = blockIdx.x * 4 + wv;
    if (n >= NN) return;
    int start = row_ptr[n], end = row_ptr[n + 1];
    int grp = lane >> 4;
    int lid = lane & 15;
    float acc[8] = {0.f, 0.f, 0.f, 0.f, 0.f, 0.f, 0.f, 0.f};
    int i = start + grp;
    for (; i + 4 < end; i += 8) {
        int s1 = sorted_src[i];
        int s2 = sorted_src[i + 4];
        u32x4 v1 = *(const u32x4*)(xin + (size_t)s1 * DIM + lid * 8);
        u32x4 v2 = *(const u32x4*)(xin + (size_t)s2 * DIM + lid * 8);
        acc[0] += bf16_lo(v1.x); acc[1] += bf16_hi(v1.x);
        acc[2] += bf16_lo(v1.y); acc[3] += bf16_hi(v1.y);
        acc[4] += bf16_lo(v1.z); acc[5] += bf16_hi(v1.z);
        acc[6] += bf16_lo(v1.w); acc[7] += bf16_hi(v1.w);
        acc[0] += bf16_lo(v2.x); acc[1] += bf16_hi(v2.x);
        acc[2] += bf16_lo(v2.y); acc[3] += bf16_hi(v2.y);
        acc[4] += bf16_lo(v2.z); acc[5] += bf16_hi(v2.z);
        acc[6] += bf16_lo(v2.w); acc[7] += bf16_hi(v2.w);
    }
    if (i < end) {
        int s = sorted_src[i];
        u32x4 v = *(const u32x4*)(xin + (size_t)s * DIM + lid * 8);
        acc[0] += bf16_lo(v.x); acc[1] += bf16_hi(v.x);
        acc[2] += bf16_lo(v.y); acc[3] += bf16_hi(v.y);
        acc[4] += bf16_lo(v.z); acc[5] += bf16_hi(v.z);
        acc[6] += bf16_lo(v.w); acc[7] += bf16_hi(v.w);
    }
#pragma unroll
    for (int k = 0; k < 8; ++k) {
        acc[k] += __shfl_xor(acc[k], 16, 64);
        acc[k] += __shfl_xor(acc[k], 32, 64);
    }
    if (grp == 0) {
        int d = end - start;
        float inv = 1.f / (float)(d > 1 ? d : 1);
        u32x4 o;
        o.x = (unsigned)f_to_bf16(acc[0] * inv) | ((unsigned)f_to_bf16(acc[1] * inv) << 16);
        o.y = (unsigned)f_to_bf16(acc[2] * inv) | ((unsigned)f_to_bf16(acc[3] * inv) << 16);
        o.z = (unsigned)f_to_bf16(acc[4] * inv) | ((unsigned)f_to_bf16(acc[5] * inv) << 16);
        o.w = (unsigned)f_to_bf16(acc[6] * inv) | ((unsigned)f_to_bf16(acc[7] * inv) << 16);
        *(u32x4*)(mean_out + (size_t)n * DIM + lid * 8) = o;
    }
}

// ---------------- fused SAGE linear: relu(mean@Wl^T + b + h@Wr^T) ----------------
// 64 rows x 16 cols per wave: 4 stacked 16x16 tiles, B-frags loaded once and
// reused 4x, A double-buffered (2 tiles = 16 outstanding 16B loads).
// mfma_f32_16x16x32_bf16 layouts (m89/m120-verified):
//   A: A[m=lane&15][k=quad*8+j]; B: B[k=quad*8+j][n=lane&15] = W[col][k..k+7];
//   C/D: col=lane&15, row=quad*4+reg.

template <bool WRITE_F32>
__global__ __launch_bounds__(256) void sage_gemm(
    const unsigned short* __restrict__ mean,   // [N,128] bf16
    const unsigned short* __restrict__ hself,  // [N,128] bf16
    const unsigned short* __restrict__ Wl,     // [128,128] bf16
    const unsigned short* __restrict__ Wr,
    const float* __restrict__ bias,            // [128] fp32
    void* __restrict__ outv) {
    int lane = threadIdx.x & 63;
    int wv = threadIdx.x >> 6;
    int quad = lane >> 4;
    int lid = lane & 15;
    int row0 = blockIdx.x * 64;
    int bcol = blockIdx.y * 64 + wv * 16 + lid;

    // B fragments: held for the whole kernel, reused by all 4 row tiles
    const unsigned short* wlp = Wl + (size_t)bcol * DIM + quad * 8;
    const unsigned short* wrp = Wr + (size_t)bcol * DIM + quad * 8;
    s16x8 bl[4], br[4];
#pragma unroll
    for (int kb = 0; kb < 4; ++kb) {
        bl[kb] = *(const s16x8*)(wlp + kb * 32);
        br[kb] = *(const s16x8*)(wrp + kb * 32);
    }

    const unsigned short* ap = mean + (size_t)(row0 + lid) * DIM + quad * 8;
    const unsigned short* hp = hself + (size_t)(row0 + lid) * DIM + quad * 8;
    const int TS = 16 * DIM;   // tile row stride in elements

    f32x4 acc[4] = {{0,0,0,0},{0,0,0,0},{0,0,0,0},{0,0,0,0}};
    s16x8 am[2][4], ah[2][4];

    // prologue: tile 0
#pragma unroll
    for (int kb = 0; kb < 4; ++kb) {
        am[0][kb] = *(const s16x8*)(ap + kb * 32);
        ah[0][kb] = *(const s16x8*)(hp + kb * 32);
    }
#pragma unroll
    for (int t = 0; t < 4; ++t) {
        int cb = t & 1, nb = (t + 1) & 1;
        if (t < 3) {
#pragma unroll
            for (int kb = 0; kb < 4; ++kb) {
                am[nb][kb] = *(const s16x8*)(ap + (t + 1) * TS + kb * 32);
                ah[nb][kb] = *(const s16x8*)(hp + (t + 1) * TS + kb * 32);
            }
        }
#pragma unroll
        for (int kb = 0; kb < 4; ++kb)
            acc[t] = __builtin_amdgcn_mfma_f32_16x16x32_bf16(am[cb][kb], bl[kb], acc[t], 0, 0, 0);
#pragma unroll
        for (int kb = 0; kb < 4; ++kb)
            acc[t] = __builtin_amdgcn_mfma_f32_16x16x32_bf16(ah[cb][kb], br[kb], acc[t], 0, 0, 0);
    }

    float bv = bias[bcol];
#pragma unroll
    for (int t = 0; t < 4; ++t) {
#pragma unroll
        for (int r = 0; r < 4; ++r) {
            int orow = row0 + t * 16 + quad * 4 + r;
            float v = fmaxf(acc[t][r] + bv, 0.f);   // relu
            if (WRITE_F32)
                ((float*)outv)[(size_t)orow * DIM + bcol] = v;
            else
                ((unsigned short*)outv)[(size_t)orow * DIM + bcol] = f_to_bf16(v);
        }
    }
}

// ---------------- launch ----------------

extern "C" void kernel_launch(void* const* d_in, const int* in_sizes, int n_in,
                              void* d_out, int out_size, void* d_ws, size_t ws_size,
                              hipStream_t stream) {
    const float* x   = (const float*)d_in[0];
    const int*   ei  = (const int*)d_in[1];
    const float* W1l = (const float*)d_in[2];
    const float* b1l = (const float*)d_in[3];
    const float* W1r = (const float*)d_in[4];
    const float* W2l = (const float*)d_in[5];
    const float* b2l = (const float*)d_in[6];
    const float* W2r = (const float*)d_in[7];
    float* out = (float*)d_out;

    const int OUT_ELEMS = NN * DIM;        // 5,120,000

    // workspace layout (256B-aligned; bsum tucked into row_ptr region slack)
    const size_t OFF_DEG  = 0;             // N ints
    const size_t OFF_ROW  = 163840;        // N+1 ints
    const size_t OFF_BSUM = 324608;        // NBLK ints
    const size_t OFF_CUR  = 327680;        // N ints
    const size_t OFF_FMT  = 491264;        // 1 int
    const size_t OFF_SRT  = 491520;        // E ints
    const size_t OFF_WB   = 3051520;       // 4 * 16384 bf16
    const size_t OFF_XB   = 3182592;       // N*128 bf16
    const size_t OFF_MEAN = 13422592;      // N*128 bf16
    const size_t OFF_H1   = 23662592;      // N*128 bf16
    const size_t NEEDED   = 33902592;

    if (ws_size < NEEDED) {
        fill_const_f32<<<(OUT_ELEMS + 255) / 256, 256, 0, stream>>>(out, OUT_ELEMS, 50.0f);
        return;
    }

    char* ws = (char*)d_ws;
    int* deg     = (int*)(ws + OFF_DEG);
    int* row_ptr = (int*)(ws + OFF_ROW);
    int* bsum    = (int*)(ws + OFF_BSUM);
    int* cursor  = (int*)(ws + OFF_CUR);
    int* fmtflag = (int*)(ws + OFF_FMT);
    int* sorted  = (int*)(ws + OFF_SRT);
    unsigned short* Wb    = (unsigned short*)(ws + OFF_WB);
    unsigned short* xb    = (unsigned short*)(ws + OFF_XB);
    unsigned short* meanb = (unsigned short*)(ws + OFF_MEAN);
    unsigned short* h1b   = (unsigned short*)(ws + OFF_H1);

    // conversions fp32 -> bf16
    cvt_f32_bf16<<<(OUT_ELEMS / 4 + 255) / 256, 256, 0, stream>>>(x, xb, OUT_ELEMS / 4);
    cvt_weights<<<dim3(16, 4), 256, 0, stream>>>(W1l, W1r, W2l, W2r, Wb);
    unsigned short* W1lb = Wb;
    unsigned short* W1rb = Wb + 16384;
    unsigned short* W2lb = Wb + 32768;
    unsigned short* W2rb = Wb + 49152;

    // CSR build
    zero_ints<<<NBLK, 256, 0, stream>>>(deg, NN);
    detect_fmt<<<1, 64, 0, stream>>>(ei, fmtflag);
    count_deg<<<(NE + 255) / 256, 256, 0, stream>>>(ei, fmtflag, deg);
    block_sums<<<NBLK, 256, 0, stream>>>(deg, bsum);
    scan_bsums<<<1, 256, 0, stream>>>(bsum, NBLK);
    scan_block<<<NBLK, 256, 0, stream>>>(deg, bsum, row_ptr, cursor);
    fill_csr<<<(NE + 255) / 256, 256, 0, stream>>>(ei, fmtflag, cursor, sorted);

    // layer 1: h1 = relu(mean(x)@W1l^T + b1l + x@W1r^T)   (bf16 out)
    aggregate<<<(NN + 3) / 4, 256, 0, stream>>>(xb, row_ptr, sorted, meanb);
    sage_gemm<false><<<dim3(NN / 64, 2), 256, 0, stream>>>(meanb, xb, W1lb, W1rb, b1l, h1b);

    // layer 2: out = relu(mean(h1)@W2l^T + b2l + h1@W2r^T)   (fp32 out)
    aggregate<<<(NN + 3) / 4, 256, 0, stream>>>(h1b, row_ptr, sorted, meanb);
    sage_gemm<true><<<dim3(NN / 64, 2), 256, 0, stream>>>(meanb, h1b, W2lb, W2rb, b2l, out);
}